// Round 1
// baseline (1090.974 us; speedup 1.0000x reference)
//
#include <hip/hip_runtime.h>

#define TOK 32768          // B*N
#define DMODEL 1024
#define NSEQ 8192
#define NCHK 32            // chunks per sequence
#define CHUNKC 256

typedef __attribute__((ext_vector_type(8))) short bf16x8;
typedef __attribute__((ext_vector_type(4))) float f32x4;

__device__ __forceinline__ unsigned short f2bf(float f) {
  unsigned u = __float_as_uint(f);
  u += 0x7fffu + ((u >> 16) & 1u);
  return (unsigned short)(u >> 16);
}
__device__ __forceinline__ float bf2f(unsigned short h) {
  return __uint_as_float(((unsigned)h) << 16);
}

typedef __attribute__((address_space(3))) unsigned int lds_u32_t;
typedef const __attribute__((address_space(1))) unsigned int glb_u32_t;

__device__ __forceinline__ void gl_lds16(const void* g, void* l) {
  __builtin_amdgcn_global_load_lds((glb_u32_t*)g, (lds_u32_t*)l, 16, 0, 0);
}

// ---------------- weight transpose to bf16 (W[R][C] -> WT[C][R]) ----------------
__global__ __launch_bounds__(256) void transpose_bf16_k(const float* __restrict__ in,
                                                        unsigned short* __restrict__ out,
                                                        int R, int C) {
  __shared__ float tile[32][33];
  const int c0 = blockIdx.x * 32, r0 = blockIdx.y * 32;
  const int tx = threadIdx.x, ty = threadIdx.y;
#pragma unroll
  for (int i = 0; i < 32; i += 8)
    tile[ty + i][tx] = in[(long)(r0 + ty + i) * C + c0 + tx];
  __syncthreads();
#pragma unroll
  for (int i = 0; i < 32; i += 8)
    out[(long)(c0 + ty + i) * R + r0 + tx] = f2bf(tile[tx][ty + i]);
}

// ---------------- RoPE cos/sin table: tab[n*32+i] = {cos,sin}(n * 10000^(-i/32)) ----
__global__ __launch_bounds__(256) void ropetab_k(float2* __restrict__ tab) {
  const int i = blockIdx.x * 256 + threadIdx.x;   // 8192*32 entries
  const int f = i & 31, n = i >> 5;
  const float invf = exp2f(-(float)f * (13.287712379549449f / 32.0f)); // log2(10000)/32
  const float ang = (float)n * invf;
  tab[i] = make_float2(cosf(ang), sinf(ang));
}

// ---------------- RMSNorm ----------------
__global__ __launch_bounds__(256) void rmsnorm_k(const float* __restrict__ x,
                                                 const float* __restrict__ scale,
                                                 float* __restrict__ xn) {
  const int row = blockIdx.x, t = threadIdx.x;
  const float4 v = ((const float4*)(x + (long)row * DMODEL))[t];
  float ss = v.x * v.x + v.y * v.y + v.z * v.z + v.w * v.w;
#pragma unroll
  for (int off = 32; off > 0; off >>= 1) ss += __shfl_down(ss, off);
  __shared__ float red[4];
  if ((t & 63) == 0) red[t >> 6] = ss;
  __syncthreads();
  const float tot = red[0] + red[1] + red[2] + red[3];
  const float r = rsqrtf(tot * (1.0f / DMODEL) + 1e-6f);
  const float4 sc = ((const float4*)scale)[t];
  float4 o;
  o.x = fminf(fmaxf(v.x * r * sc.x, -60000.f), 60000.f);
  o.y = fminf(fmaxf(v.y * r * sc.y, -60000.f), 60000.f);
  o.z = fminf(fmaxf(v.z * r * sc.z, -60000.f), 60000.f);
  o.w = fminf(fmaxf(v.w * r * sc.w, -60000.f), 60000.f);
  ((float4*)(xn + (long)row * DMODEL))[t] = o;
}

// ---------------- depthwise causal conv (K=4) + SiLU, bf16 out ----------------
__global__ __launch_bounds__(256) void conv_silu_k(const float* __restrict__ xn,
                                                   const float* __restrict__ w,
                                                   const float* __restrict__ cb,
                                                   unsigned short* __restrict__ xc) {
  const long gid = (long)blockIdx.x * 256 + threadIdx.x;
  const long base = gid * 4;
  const long row = base >> 10;
  const int d0 = (int)(base & 1023);
  const int n = (int)(row & (NSEQ - 1));
  float wl[4][4];
#pragma unroll
  for (int i = 0; i < 4; ++i) {
    const float4 t4 = *(const float4*)(w + (d0 + i) * 4);
    wl[i][0] = t4.x; wl[i][1] = t4.y; wl[i][2] = t4.z; wl[i][3] = t4.w;
  }
  float o[4] = {0.f, 0.f, 0.f, 0.f};
#pragma unroll
  for (int k = 0; k < 4; ++k) {
    const int sn = n - 3 + k;
    if (sn >= 0) {
      const float4 xv = *(const float4*)(xn + (row - 3 + k) * DMODEL + d0);
      o[0] += xv.x * wl[0][k]; o[1] += xv.y * wl[1][k];
      o[2] += xv.z * wl[2][k]; o[3] += xv.w * wl[3][k];
    }
  }
  const float4 cb4 = *(const float4*)(cb + d0);
  ushort4 st;
  { const float t = o[0] + cb4.x; st.x = f2bf(t / (1.f + expf(-t))); }
  { const float t = o[1] + cb4.y; st.y = f2bf(t / (1.f + expf(-t))); }
  { const float t = o[2] + cb4.z; st.z = f2bf(t / (1.f + expf(-t))); }
  { const float t = o[3] + cb4.w; st.w = f2bf(t / (1.f + expf(-t))); }
  *(ushort4*)(xc + base) = st;
}

// ---------------- GEMM: C[M][Ncols] = A[M][K] @ BT[Ncols][K]^T  (bf16 in, f32 acc) ---
// EPI==0: fused in_proj epilogue (dt / rope(v) / gate). EPI==1: residual add -> out.
template <int EPI>
__global__ __launch_bounds__(256) void gemm_bt(const unsigned short* __restrict__ A,
                                               const unsigned short* __restrict__ BT,
                                               int K,
                                               float* dtb, float* vrot,
                                               unsigned short* gateb,
                                               const float* __restrict__ dt_bias,
                                               const float2* __restrict__ tab,
                                               float* outp, const float* __restrict__ resid) {
  __shared__ unsigned short As[128 * 64];
  __shared__ unsigned short Bs[128 * 64];
  const int tid = threadIdx.x;
  const int l = tid & 63;
  const int w = tid >> 6;
  const int wr = w >> 1, wc = w & 1;
  const int bm = blockIdx.y, bn = blockIdx.x;

  f32x4 acc[4][4];
#pragma unroll
  for (int m = 0; m < 4; ++m)
#pragma unroll
    for (int n = 0; n < 4; ++n) acc[m][n] = {0.f, 0.f, 0.f, 0.f};

  const int lr = l >> 3;          // row within 8-row chunk
  const int lc = (l & 7) * 8;     // col element within 64
  const unsigned short* aG[4];
  const unsigned short* bG[4];
  unsigned short* aL[4];
  unsigned short* bL[4];
#pragma unroll
  for (int i = 0; i < 4; ++i) {
    const int ch = w + i * 4;
    aG[i] = A + ((long)(bm * 128 + ch * 8 + lr)) * K + lc;
    bG[i] = BT + ((long)(bn * 128 + ch * 8 + lr)) * K + lc;
    aL[i] = &As[ch * 512];
    bL[i] = &Bs[ch * 512];
  }

  const int nkt = K >> 6;
  for (int kt = 0; kt < nkt; ++kt) {
    const int k0 = kt * 64;
#pragma unroll
    for (int i = 0; i < 4; ++i) {
      gl_lds16(aG[i] + k0, aL[i]);
      gl_lds16(bG[i] + k0, bL[i]);
    }
    __syncthreads();   // drains vmcnt -> staging complete
#pragma unroll
    for (int kk = 0; kk < 2; ++kk) {
      bf16x8 af[4], bfr[4];
#pragma unroll
      for (int m = 0; m < 4; ++m)
        af[m] = *(const bf16x8*)&As[(wr * 64 + m * 16 + (l & 15)) * 64 + kk * 32 + (l >> 4) * 8];
#pragma unroll
      for (int n = 0; n < 4; ++n)
        bfr[n] = *(const bf16x8*)&Bs[(wc * 64 + n * 16 + (l & 15)) * 64 + kk * 32 + (l >> 4) * 8];
#pragma unroll
      for (int m = 0; m < 4; ++m)
#pragma unroll
        for (int n = 0; n < 4; ++n)
          acc[m][n] = __builtin_amdgcn_mfma_f32_16x16x32_bf16(af[m], bfr[n], acc[m][n], 0, 0, 0);
    }
    __syncthreads();   // before next stage overwrites LDS
  }

  const int rbase = bm * 128 + wr * 64;
  const int cbase = bn * 128 + wc * 64;
  const int lr4 = (l >> 4) * 4;
  const int lc16 = l & 15;

  if constexpr (EPI == 0) {
    const int seg = cbase >> 10;   // block-uniform: 0=dt, 1=v, 2=gate
    if (seg == 0) {
#pragma unroll
      for (int m = 0; m < 4; ++m)
#pragma unroll
        for (int n = 0; n < 4; ++n) {
          const int c = (cbase & 1023) + n * 16 + lc16;
          const float bias = dt_bias[c];
#pragma unroll
          for (int j = 0; j < 4; ++j) {
            const int row = rbase + m * 16 + lr4 + j;
            const float t = acc[m][n][j] + bias;
            const float sp = fmaxf(t, 0.f) + log1pf(expf(-fabsf(t)));
            dtb[(long)row * DMODEL + c] = fminf(fmaxf(sp, 0.001f), 2.0f);
          }
        }
    } else if (seg == 1) {
#pragma unroll
      for (int m = 0; m < 4; ++m)
#pragma unroll
        for (int n = 0; n < 2; ++n) {
          const int dd = n * 16 + lc16;          // 0..31 within head
          const int c = (cbase & 1023) + dd;
#pragma unroll
          for (int j = 0; j < 4; ++j) {
            const int row = rbase + m * 16 + lr4 + j;
            const int pos = row & (NSEQ - 1);
            const float2 cs = tab[pos * 32 + dd];
            const float v1 = acc[m][n][j], v2 = acc[m][n + 2][j];
            vrot[(long)row * DMODEL + c]      = v1 * cs.x - v2 * cs.y;
            vrot[(long)row * DMODEL + c + 32] = v1 * cs.y + v2 * cs.x;
          }
        }
    } else {
#pragma unroll
      for (int m = 0; m < 4; ++m)
#pragma unroll
        for (int n = 0; n < 4; ++n) {
          const int c = (cbase & 1023) + n * 16 + lc16;
#pragma unroll
          for (int j = 0; j < 4; ++j) {
            const int row = rbase + m * 16 + lr4 + j;
            gateb[(long)row * DMODEL + c] = f2bf(1.f / (1.f + expf(-acc[m][n][j])));
          }
        }
    }
  } else {
#pragma unroll
    for (int m = 0; m < 4; ++m)
#pragma unroll
      for (int n = 0; n < 4; ++n) {
        const int col = cbase + n * 16 + lc16;
#pragma unroll
        for (int j = 0; j < 4; ++j) {
          const int row = rbase + m * 16 + lr4 + j;
          const long o = (long)row * DMODEL + col;
          outp[o] = resid[o] + acc[m][n][j];
        }
      }
  }
}

// ---------------- scan pass 1: per (b,chunk,d) -> Lmax, Llast, bout ----------------
__global__ __launch_bounds__(256) void scan1_k(const float* __restrict__ dt,
                                               const float* __restrict__ vrot,
                                               float* __restrict__ Lmax,
                                               float* __restrict__ Llast,
                                               float* __restrict__ bout) {
  const int idx = blockIdx.x * 256 + threadIdx.x;   // B*NCHK*D = 131072
  const int d = idx & 1023;
  const int ch = (idx >> 10) & 31;
  const int b = idx >> 15;
  const long base = ((long)b * NSEQ + ch * CHUNKC) * DMODEL + d;
  float run = 0.f, lm = -1e30f;
#pragma unroll 4
  for (int c = 0; c < CHUNKC; ++c) {
    run -= dt[base + (long)c * DMODEL];
    lm = fmaxf(lm, fminf(fmaxf(run, -20.f), 0.f));
  }
  const float llast = fminf(fmaxf(run, -20.f), 0.f);
  run = 0.f;
  float s = 0.f;
#pragma unroll 4
  for (int c = 0; c < CHUNKC; ++c) {
    const float dtv = dt[base + (long)c * DMODEL];
    const float vv = vrot[base + (long)c * DMODEL] * dtv;
    run -= dtv;
    const float L = fminf(fmaxf(run, -20.f), 0.f);
    s += expf(lm - L) * vv;
  }
  Lmax[idx] = lm;
  Llast[idx] = llast;
  bout[idx] = expf(llast - lm) * s;
}

// ---------------- scan pass 2: cross-chunk scan per (b,d) -> carry ----------------
__global__ __launch_bounds__(256) void scan2_k(const float* __restrict__ Llast,
                                               const float* __restrict__ bout,
                                               float* __restrict__ carry) {
  const int idx = blockIdx.x * 256 + threadIdx.x;   // B*D = 4096
  const int d = idx & 1023;
  const int b = idx >> 10;
  const long base = (long)b * (NCHK * DMODEL) + d;
  float cd[NCHK];
  float run = 0.f, stab = -1e30f;
#pragma unroll
  for (int ch = 0; ch < NCHK; ++ch) {
    run += Llast[base + ch * DMODEL];
    cd[ch] = fminf(fmaxf(run, -80.f), 0.f);
    stab = fmaxf(stab, cd[ch]);
  }
  float acc = 0.f;
#pragma unroll
  for (int ch = 0; ch < NCHK; ++ch) {
    const float ncd = fminf(fmaxf(cd[ch] - stab, -20.f), 0.f);
    carry[base + ch * DMODEL] = acc * expf(ncd);
    acc += bout[base + ch * DMODEL] * expf(-ncd);
  }
}

// ---------------- scan pass 3: outputs (writes final IN PLACE over dt) -------------
__global__ __launch_bounds__(256) void scan3_k(const float* dt,          // no restrict: aliases fin
                                               const float* __restrict__ vrot,
                                               const float* __restrict__ Lmax,
                                               const float* __restrict__ carry,
                                               float* fin) {             // no restrict
  const int idx = blockIdx.x * 256 + threadIdx.x;
  const int d = idx & 1023;
  const int ch = (idx >> 10) & 31;
  const int b = idx >> 15;
  const long base = ((long)b * NSEQ + ch * CHUNKC) * DMODEL + d;
  const float lm = Lmax[idx];
  const float ce = carry[idx] * expf(lm);
  float run = 0.f, s = 0.f;
#pragma unroll 4
  for (int c = 0; c < CHUNKC; ++c) {
    const float dtv = dt[base + (long)c * DMODEL];
    const float vv = vrot[base + (long)c * DMODEL] * dtv;
    run -= dtv;
    const float L = fminf(fmaxf(run, -20.f), 0.f);
    const float ep = expf(L - lm);
    s += expf(lm - L) * vv;
    fin[base + (long)c * DMODEL] = ep * s + ce * ep;
  }
}

// ---------------- head mix (16x16) * gate -> A2 bf16 ----------------
__global__ __launch_bounds__(256) void headmix_k(const float* __restrict__ fin,
                                                 const unsigned short* __restrict__ gateb,
                                                 const float* __restrict__ hm,
                                                 unsigned short* __restrict__ A2) {
  __shared__ float mixs[256];
  const int t = threadIdx.x;
  mixs[t] = hm[t];
  __syncthreads();
  const long row = (long)blockIdx.x * 4 + (t >> 6);
  const int dd = t & 63;
  const float* f = fin + row * DMODEL + dd;
  float fv[16];
#pragma unroll
  for (int h = 0; h < 16; ++h) fv[h] = f[h * 64];
#pragma unroll
  for (int m = 0; m < 16; ++m) {
    float o = 0.f;
#pragma unroll
    for (int h = 0; h < 16; ++h) o += fv[h] * mixs[h * 16 + m];
    const long c = row * DMODEL + m * 64 + dd;
    A2[c] = f2bf(o * bf2f(gateb[c]));
  }
}

extern "C" void kernel_launch(void* const* d_in, const int* in_sizes, int n_in,
                              void* d_out, int out_size, void* d_ws, size_t ws_size,
                              hipStream_t stream) {
  const float* x        = (const float*)d_in[0];
  const float* nscale   = (const float*)d_in[1];
  const float* conv_w   = (const float*)d_in[2];
  const float* conv_b   = (const float*)d_in[3];
  const float* in_proj  = (const float*)d_in[4];
  const float* dt_bias  = (const float*)d_in[5];
  const float* head_mix = (const float*)d_in[6];
  const float* out_proj = (const float*)d_in[7];
  float* out = (float*)d_out;

  char* p = (char*)d_ws;
  unsigned short* W1T = (unsigned short*)p; p += (size_t)3072 * 1024 * 2;
  unsigned short* W2T = (unsigned short*)p; p += (size_t)1024 * 1024 * 2;
  float2* tab  = (float2*)p; p += (size_t)NSEQ * 32 * sizeof(float2);
  float* Lmax  = (float*)p;  p += (size_t)131072 * 4;
  float* Llast = (float*)p;  p += (size_t)131072 * 4;
  float* bout  = (float*)p;  p += (size_t)131072 * 4;
  float* carry = (float*)p;  p += (size_t)131072 * 4;
  float* xn    = (float*)p;  p += (size_t)TOK * DMODEL * 4;  // reused: dt, then final
  unsigned short* xc = (unsigned short*)p; p += (size_t)TOK * DMODEL * 2; // reused: A2
  float* vrot  = (float*)p;  p += (size_t)TOK * DMODEL * 4;
  unsigned short* gateb = (unsigned short*)p; p += (size_t)TOK * DMODEL * 2;

  transpose_bf16_k<<<dim3(96, 32), dim3(32, 8), 0, stream>>>(in_proj, W1T, 1024, 3072);
  transpose_bf16_k<<<dim3(32, 32), dim3(32, 8), 0, stream>>>(out_proj, W2T, 1024, 1024);
  ropetab_k<<<1024, 256, 0, stream>>>(tab);
  rmsnorm_k<<<TOK, 256, 0, stream>>>(x, nscale, xn);
  conv_silu_k<<<TOK * DMODEL / 1024, 256, 0, stream>>>(xn, conv_w, conv_b, xc);

  float* dtb = xn;  // xn no longer needed; reuse for dt
  gemm_bt<0><<<dim3(24, 256), 256, 0, stream>>>(xc, W1T, 1024, dtb, vrot, gateb,
                                                dt_bias, tab, nullptr, nullptr);
  scan1_k<<<512, 256, 0, stream>>>(dtb, vrot, Lmax, Llast, bout);
  scan2_k<<<16, 256, 0, stream>>>(Llast, bout, carry);
  scan3_k<<<512, 256, 0, stream>>>(dtb, vrot, Lmax, carry, dtb /* in-place final */);
  headmix_k<<<TOK / 4, 256, 0, stream>>>(dtb, gateb, head_mix, xc /* A2 */);
  gemm_bt<1><<<dim3(8, 256), 256, 0, stream>>>(xc, W2T, 1024, nullptr, nullptr, nullptr,
                                               nullptr, nullptr, out, x);
}

// Round 2
// 812.844 us; speedup vs baseline: 1.3422x; 1.3422x over previous
//
#include <hip/hip_runtime.h>

#define TOK 32768          // B*N
#define DMODEL 1024
#define NSEQ 8192
#define NCHK 32            // chunks per sequence
#define CHUNKC 256

typedef __attribute__((ext_vector_type(8))) short bf16x8;
typedef __attribute__((ext_vector_type(4))) float f32x4;

__device__ __forceinline__ unsigned short f2bf(float f) {
  unsigned u = __float_as_uint(f);
  u += 0x7fffu + ((u >> 16) & 1u);
  return (unsigned short)(u >> 16);
}
__device__ __forceinline__ float bf2f(unsigned short h) {
  return __uint_as_float(((unsigned)h) << 16);
}

typedef __attribute__((address_space(3))) unsigned int lds_u32_t;
typedef const __attribute__((address_space(1))) unsigned int glb_u32_t;

__device__ __forceinline__ void gl_lds16(const void* g, void* l) {
  __builtin_amdgcn_global_load_lds((glb_u32_t*)g, (lds_u32_t*)l, 16, 0, 0);
}

// ---------------- weight transpose to bf16 (W[R][C] -> WT[C][R]) ----------------
__global__ __launch_bounds__(256) void transpose_bf16_k(const float* __restrict__ in,
                                                        unsigned short* __restrict__ out,
                                                        int R, int C) {
  __shared__ float tile[32][33];
  const int c0 = blockIdx.x * 32, r0 = blockIdx.y * 32;
  const int tx = threadIdx.x, ty = threadIdx.y;
#pragma unroll
  for (int i = 0; i < 32; i += 8)
    tile[ty + i][tx] = in[(long)(r0 + ty + i) * C + c0 + tx];
  __syncthreads();
#pragma unroll
  for (int i = 0; i < 32; i += 8)
    out[(long)(c0 + ty + i) * R + r0 + tx] = f2bf(tile[tx][ty + i]);
}

// ---------------- RoPE cos/sin table ----------------
__global__ __launch_bounds__(256) void ropetab_k(float2* __restrict__ tab) {
  const int i = blockIdx.x * 256 + threadIdx.x;   // 8192*32 entries
  const int f = i & 31, n = i >> 5;
  const float invf = exp2f(-(float)f * (13.287712379549449f / 32.0f)); // log2(10000)/32
  const float ang = (float)n * invf;
  tab[i] = make_float2(cosf(ang), sinf(ang));
}

// ---------------- fused RMSNorm + depthwise causal conv(K=4) + SiLU -> bf16 -------
__global__ __launch_bounds__(256) void rmsconv_k(const float* __restrict__ x,
                                                 const float* __restrict__ scale,
                                                 const float* __restrict__ w,
                                                 const float* __restrict__ cb,
                                                 unsigned short* __restrict__ xc) {
  __shared__ float xs[11][1024];   // rows row0-3 .. row0+7 normalized
  __shared__ float red[4];
  const int t = threadIdx.x;
  const long row0 = (long)blockIdx.x * 8;
  const bool seqstart = ((row0 & (NSEQ - 1)) == 0);
  const float4 sc = ((const float4*)scale)[t];
  for (int i = 0; i < 11; ++i) {
    if (i < 3 && seqstart) {            // block-uniform branch
      ((float4*)xs[i])[t] = make_float4(0.f, 0.f, 0.f, 0.f);
      continue;
    }
    const long r = row0 - 3 + i;
    const float4 v = ((const float4*)(x + r * DMODEL))[t];
    float ss = v.x * v.x + v.y * v.y + v.z * v.z + v.w * v.w;
#pragma unroll
    for (int off = 32; off > 0; off >>= 1) ss += __shfl_down(ss, off);
    if ((t & 63) == 0) red[t >> 6] = ss;
    __syncthreads();
    const float tot = red[0] + red[1] + red[2] + red[3];
    const float rr = rsqrtf(tot * (1.0f / DMODEL) + 1e-6f);
    float4 o;
    o.x = fminf(fmaxf(v.x * rr * sc.x, -60000.f), 60000.f);
    o.y = fminf(fmaxf(v.y * rr * sc.y, -60000.f), 60000.f);
    o.z = fminf(fmaxf(v.z * rr * sc.z, -60000.f), 60000.f);
    o.w = fminf(fmaxf(v.w * rr * sc.w, -60000.f), 60000.f);
    ((float4*)xs[i])[t] = o;
    __syncthreads();                     // xs[i] visible + red free for next row
  }
  __syncthreads();
  const int d0 = t * 4;
  float wl[4][4];
#pragma unroll
  for (int j = 0; j < 4; ++j) {
    const float4 t4 = *(const float4*)(w + (d0 + j) * 4);
    wl[j][0] = t4.x; wl[j][1] = t4.y; wl[j][2] = t4.z; wl[j][3] = t4.w;
  }
  const float4 cb4 = ((const float4*)cb)[t];
#pragma unroll
  for (int orow = 0; orow < 8; ++orow) {
    float o[4] = {0.f, 0.f, 0.f, 0.f};
#pragma unroll
    for (int k = 0; k < 4; ++k) {
      const float4 xv = ((const float4*)xs[orow + k])[t];
      o[0] += xv.x * wl[0][k]; o[1] += xv.y * wl[1][k];
      o[2] += xv.z * wl[2][k]; o[3] += xv.w * wl[3][k];
    }
    ushort4 st;
    { const float a = o[0] + cb4.x; st.x = f2bf(a / (1.f + expf(-a))); }
    { const float a = o[1] + cb4.y; st.y = f2bf(a / (1.f + expf(-a))); }
    { const float a = o[2] + cb4.z; st.z = f2bf(a / (1.f + expf(-a))); }
    { const float a = o[3] + cb4.w; st.w = f2bf(a / (1.f + expf(-a))); }
    *(ushort4*)(xc + (row0 + orow) * DMODEL + d0) = st;
  }
}

// ---------------- GEMM: C[M][Ncols] = A[M][K] @ BT[Ncols][K]^T  (bf16, f32 acc) ---
// T2 st-swizzle: LDS linear dest for global_load_lds, pre-swizzled global source,
// swizzled ds_read. T1 bijective XCD swizzle on block ids (bm-major chunks).
// EPI==0: fused in_proj epilogue (dt f32 / rope(v)->bf16 / gate->bf16).
// EPI==1: residual add -> f32 out.
template <int EPI>
__global__ __launch_bounds__(256) void gemm_bt(const unsigned short* __restrict__ A,
                                               const unsigned short* __restrict__ BT,
                                               int K,
                                               float* dtb, unsigned short* vrotb,
                                               unsigned short* gateb,
                                               const float* __restrict__ dt_bias,
                                               const float2* __restrict__ tab,
                                               float* outp, const float* __restrict__ resid) {
  __shared__ unsigned short As[128 * 64];
  __shared__ unsigned short Bs[128 * 64];
  const int tid = threadIdx.x;
  const int l = tid & 63;
  const int w = tid >> 6;
  const int wr = w >> 1, wc = w & 1;

  // T1: XCD-aware bijective remap, bm-major work order
  const int lin = blockIdx.y * gridDim.x + blockIdx.x;
  const int nwg = gridDim.x * gridDim.y;
  const int cpx = nwg >> 3;
  const int swz = (lin & 7) * cpx + (lin >> 3);
  const int bm = swz / gridDim.x;
  const int bn = swz - bm * gridDim.x;

  f32x4 acc[4][4];
#pragma unroll
  for (int m = 0; m < 4; ++m)
#pragma unroll
    for (int n = 0; n < 4; ++n) acc[m][n] = {0.f, 0.f, 0.f, 0.f};

  const int lr = l >> 3;                       // row within 8-row chunk
  const int lc = ((l & 7) ^ lr) * 8;           // T2: inverse-swizzled source col
  const unsigned short* aG[4];
  const unsigned short* bG[4];
  unsigned short* aL[4];
  unsigned short* bL[4];
#pragma unroll
  for (int i = 0; i < 4; ++i) {
    const int ch = w + i * 4;
    aG[i] = A + ((long)(bm * 128 + ch * 8 + lr)) * K + lc;
    bG[i] = BT + ((long)(bn * 128 + ch * 8 + lr)) * K + lc;
    aL[i] = &As[ch * 512];
    bL[i] = &Bs[ch * 512];
  }

  // T2 read-side swizzled column (frag row % 8 == l % 8 for both A and B)
  const int sw = (l & 7) * 8;
  const int col0 = ((l >> 4) * 8) ^ sw;
  const int col1 = (32 + (l >> 4) * 8) ^ sw;

  const int nkt = K >> 6;
  for (int kt = 0; kt < nkt; ++kt) {
    const int k0 = kt * 64;
#pragma unroll
    for (int i = 0; i < 4; ++i) {
      gl_lds16(aG[i] + k0, aL[i]);
      gl_lds16(bG[i] + k0, bL[i]);
    }
    __syncthreads();   // drains vmcnt -> staging complete
#pragma unroll
    for (int kk = 0; kk < 2; ++kk) {
      const int ck = kk ? col1 : col0;
      bf16x8 af[4], bfr[4];
#pragma unroll
      for (int m = 0; m < 4; ++m)
        af[m] = *(const bf16x8*)&As[(wr * 64 + m * 16 + (l & 15)) * 64 + ck];
#pragma unroll
      for (int n = 0; n < 4; ++n)
        bfr[n] = *(const bf16x8*)&Bs[(wc * 64 + n * 16 + (l & 15)) * 64 + ck];
#pragma unroll
      for (int m = 0; m < 4; ++m)
#pragma unroll
        for (int n = 0; n < 4; ++n)
          acc[m][n] = __builtin_amdgcn_mfma_f32_16x16x32_bf16(af[m], bfr[n], acc[m][n], 0, 0, 0);
    }
    __syncthreads();   // before next stage overwrites LDS
  }

  const int rbase = bm * 128 + wr * 64;
  const int cbase = bn * 128 + wc * 64;
  const int lr4 = (l >> 4) * 4;
  const int lc16 = l & 15;

  if constexpr (EPI == 0) {
    const int seg = cbase >> 10;   // block-uniform: 0=dt, 1=v, 2=gate
    if (seg == 0) {
#pragma unroll
      for (int m = 0; m < 4; ++m)
#pragma unroll
        for (int n = 0; n < 4; ++n) {
          const int c = (cbase & 1023) + n * 16 + lc16;
          const float bias = dt_bias[c];
#pragma unroll
          for (int j = 0; j < 4; ++j) {
            const int row = rbase + m * 16 + lr4 + j;
            const float a = acc[m][n][j] + bias;
            const float sp = fmaxf(a, 0.f) + log1pf(expf(-fabsf(a)));
            dtb[(long)row * DMODEL + c] = fminf(fmaxf(sp, 0.001f), 2.0f);
          }
        }
    } else if (seg == 1) {
#pragma unroll
      for (int m = 0; m < 4; ++m)
#pragma unroll
        for (int n = 0; n < 2; ++n) {
          const int dd = n * 16 + lc16;          // 0..31 within head
          const int c = (cbase & 1023) + dd;
#pragma unroll
          for (int j = 0; j < 4; ++j) {
            const int row = rbase + m * 16 + lr4 + j;
            const int pos = row & (NSEQ - 1);
            const float2 cs = tab[pos * 32 + dd];
            const float v1 = acc[m][n][j], v2 = acc[m][n + 2][j];
            vrotb[(long)row * DMODEL + c]      = f2bf(v1 * cs.x - v2 * cs.y);
            vrotb[(long)row * DMODEL + c + 32] = f2bf(v1 * cs.y + v2 * cs.x);
          }
        }
    } else {
#pragma unroll
      for (int m = 0; m < 4; ++m)
#pragma unroll
        for (int n = 0; n < 4; ++n) {
          const int c = (cbase & 1023) + n * 16 + lc16;
#pragma unroll
          for (int j = 0; j < 4; ++j) {
            const int row = rbase + m * 16 + lr4 + j;
            gateb[(long)row * DMODEL + c] = f2bf(1.f / (1.f + expf(-acc[m][n][j])));
          }
        }
    }
  } else {
#pragma unroll
    for (int m = 0; m < 4; ++m)
#pragma unroll
      for (int n = 0; n < 4; ++n) {
        const int col = cbase + n * 16 + lc16;
#pragma unroll
        for (int j = 0; j < 4; ++j) {
          const int row = rbase + m * 16 + lr4 + j;
          const long o = (long)row * DMODEL + col;
          outp[o] = resid[o] + acc[m][n][j];
        }
      }
  }
}

// ---------------- scan pass 1 (single pass, stabilizer lm=0) ----------------
__global__ __launch_bounds__(256) void scan1_k(const float* __restrict__ dt,
                                               const unsigned short* __restrict__ vrotb,
                                               float* __restrict__ Llast,
                                               float* __restrict__ bout) {
  const int idx = blockIdx.x * 256 + threadIdx.x;   // B*NCHK*D = 131072
  const int d = idx & 1023;
  const int ch = (idx >> 10) & 31;
  const int b = idx >> 15;
  const long base = ((long)b * NSEQ + ch * CHUNKC) * DMODEL + d;
  float run = 0.f, s = 0.f, L = 0.f;
#pragma unroll 4
  for (int c = 0; c < CHUNKC; ++c) {
    const float dtv = dt[base + (long)c * DMODEL];
    const float vv = bf2f(vrotb[base + (long)c * DMODEL]) * dtv;
    run -= dtv;
    L = fminf(fmaxf(run, -20.f), 0.f);
    s += expf(-L) * vv;
  }
  Llast[idx] = L;
  bout[idx] = expf(L) * s;
}

// ---------------- scan pass 2: cross-chunk scan per (b,d) -> carry ----------------
__global__ __launch_bounds__(256) void scan2_k(const float* __restrict__ Llast,
                                               const float* __restrict__ bout,
                                               float* __restrict__ carry) {
  const int idx = blockIdx.x * 256 + threadIdx.x;   // B*D = 4096
  const int d = idx & 1023;
  const int b = idx >> 10;
  const long base = (long)b * (NCHK * DMODEL) + d;
  float cd[NCHK];
  float run = 0.f, stab = -1e30f;
#pragma unroll
  for (int ch = 0; ch < NCHK; ++ch) {
    run += Llast[base + ch * DMODEL];
    cd[ch] = fminf(fmaxf(run, -80.f), 0.f);
    stab = fmaxf(stab, cd[ch]);
  }
  float acc = 0.f;
#pragma unroll
  for (int ch = 0; ch < NCHK; ++ch) {
    const float ncd = fminf(fmaxf(cd[ch] - stab, -20.f), 0.f);
    carry[base + ch * DMODEL] = acc * expf(ncd);
    acc += bout[base + ch * DMODEL] * expf(-ncd);
  }
}

// ------- scan pass 3: final = exp(L)*(cumsum(exp(-L)*v*dt) + carry), bf16 IN PLACE over vrot
__global__ __launch_bounds__(256) void scan3_k(const float* __restrict__ dt,
                                               unsigned short* vrotb,   // read v / write final
                                               const float* __restrict__ carry) {
  const int idx = blockIdx.x * 256 + threadIdx.x;
  const int d = idx & 1023;
  const int ch = (idx >> 10) & 31;
  const int b = idx >> 15;
  const long base = ((long)b * NSEQ + ch * CHUNKC) * DMODEL + d;
  const float ce = carry[idx];
  float run = 0.f, s = 0.f;
#pragma unroll 4
  for (int c = 0; c < CHUNKC; ++c) {
    const long o = base + (long)c * DMODEL;
    const float dtv = dt[o];
    const float vv = bf2f(vrotb[o]) * dtv;
    run -= dtv;
    const float L = fminf(fmaxf(run, -20.f), 0.f);
    s += expf(-L) * vv;
    vrotb[o] = f2bf(expf(L) * (s + ce));
  }
}

// ---------------- head mix (16x16) * gate -> A2 bf16 ----------------
__global__ __launch_bounds__(256) void headmix_k(const unsigned short* __restrict__ fin,
                                                 const unsigned short* __restrict__ gateb,
                                                 const float* __restrict__ hm,
                                                 unsigned short* __restrict__ A2) {
  __shared__ float mixs[256];
  const int t = threadIdx.x;
  mixs[t] = hm[t];
  __syncthreads();
  const long row = (long)blockIdx.x * 4 + (t >> 6);
  const int dd = t & 63;
  const unsigned short* f = fin + row * DMODEL + dd;
  float fv[16];
#pragma unroll
  for (int h = 0; h < 16; ++h) fv[h] = bf2f(f[h * 64]);
#pragma unroll
  for (int m = 0; m < 16; ++m) {
    float o = 0.f;
#pragma unroll
    for (int h = 0; h < 16; ++h) o += fv[h] * mixs[h * 16 + m];
    const long c = row * DMODEL + m * 64 + dd;
    A2[c] = f2bf(o * bf2f(gateb[c]));
  }
}

extern "C" void kernel_launch(void* const* d_in, const int* in_sizes, int n_in,
                              void* d_out, int out_size, void* d_ws, size_t ws_size,
                              hipStream_t stream) {
  const float* x        = (const float*)d_in[0];
  const float* nscale   = (const float*)d_in[1];
  const float* conv_w   = (const float*)d_in[2];
  const float* conv_b   = (const float*)d_in[3];
  const float* in_proj  = (const float*)d_in[4];
  const float* dt_bias  = (const float*)d_in[5];
  const float* head_mix = (const float*)d_in[6];
  const float* out_proj = (const float*)d_in[7];
  float* out = (float*)d_out;

  char* p = (char*)d_ws;
  unsigned short* W1T = (unsigned short*)p; p += (size_t)3072 * 1024 * 2;
  unsigned short* W2T = (unsigned short*)p; p += (size_t)1024 * 1024 * 2;
  float2* tab  = (float2*)p; p += (size_t)NSEQ * 32 * sizeof(float2);
  float* Llast = (float*)p;  p += (size_t)131072 * 4;
  float* bout  = (float*)p;  p += (size_t)131072 * 4;
  float* carry = (float*)p;  p += (size_t)131072 * 4;
  float* dtb   = (float*)p;  p += (size_t)TOK * DMODEL * 4;
  unsigned short* xc    = (unsigned short*)p; p += (size_t)TOK * DMODEL * 2; // reused: A2
  unsigned short* vrotb = (unsigned short*)p; p += (size_t)TOK * DMODEL * 2; // reused: final
  unsigned short* gateb = (unsigned short*)p; p += (size_t)TOK * DMODEL * 2;

  transpose_bf16_k<<<dim3(96, 32), dim3(32, 8), 0, stream>>>(in_proj, W1T, 1024, 3072);
  transpose_bf16_k<<<dim3(32, 32), dim3(32, 8), 0, stream>>>(out_proj, W2T, 1024, 1024);
  ropetab_k<<<1024, 256, 0, stream>>>(tab);
  rmsconv_k<<<TOK / 8, 256, 0, stream>>>(x, nscale, conv_w, conv_b, xc);

  gemm_bt<0><<<dim3(24, 256), 256, 0, stream>>>(xc, W1T, 1024, dtb, vrotb, gateb,
                                                dt_bias, tab, nullptr, nullptr);
  scan1_k<<<512, 256, 0, stream>>>(dtb, vrotb, Llast, bout);
  scan2_k<<<16, 256, 0, stream>>>(Llast, bout, carry);
  scan3_k<<<512, 256, 0, stream>>>(dtb, vrotb, carry);
  headmix_k<<<TOK / 4, 256, 0, stream>>>(vrotb, gateb, head_mix, xc /* A2 */);
  gemm_bt<1><<<dim3(8, 256), 256, 0, stream>>>(xc, W2T, 1024, nullptr, nullptr, nullptr,
                                               nullptr, nullptr, out, x);
}

// Round 3
// 700.918 us; speedup vs baseline: 1.5565x; 1.1597x over previous
//
#include <hip/hip_runtime.h>

#define TOK 32768          // B*N
#define DMODEL 1024
#define NSEQ 8192
#define NCHK 32            // chunks per sequence
#define CHUNKC 256
#define KDIM 1024
#define NKT (KDIM / 64)
#define LOG2E 1.44269504f

typedef __attribute__((ext_vector_type(8))) short bf16x8;
typedef __attribute__((ext_vector_type(4))) float f32x4;

__device__ __forceinline__ unsigned short f2bf(float f) {
  unsigned u = __float_as_uint(f);
  u += 0x7fffu + ((u >> 16) & 1u);
  return (unsigned short)(u >> 16);
}
__device__ __forceinline__ float bf2f(unsigned short h) {
  return __uint_as_float(((unsigned)h) << 16);
}
__device__ __forceinline__ float sigm(float x) {   // sigmoid via exp2+rcp
  return __builtin_amdgcn_rcpf(1.f + exp2f(-LOG2E * x));
}

typedef __attribute__((address_space(3))) unsigned int lds_u32_t;
typedef const __attribute__((address_space(1))) unsigned int glb_u32_t;

__device__ __forceinline__ void gl_lds16(const void* g, void* l) {
  __builtin_amdgcn_global_load_lds((glb_u32_t*)g, (lds_u32_t*)l, 16, 0, 0);
}

// ---------------- weight transpose to bf16 (W[R][C] -> WT[C][R]) ----------------
__global__ __launch_bounds__(256) void transpose_bf16_k(const float* __restrict__ in,
                                                        unsigned short* __restrict__ out,
                                                        int R, int C) {
  __shared__ float tile[32][33];
  const int c0 = blockIdx.x * 32, r0 = blockIdx.y * 32;
  const int tx = threadIdx.x, ty = threadIdx.y;
#pragma unroll
  for (int i = 0; i < 32; i += 8)
    tile[ty + i][tx] = in[(long)(r0 + ty + i) * C + c0 + tx];
  __syncthreads();
#pragma unroll
  for (int i = 0; i < 32; i += 8)
    out[(long)(c0 + ty + i) * R + r0 + tx] = f2bf(tile[tx][ty + i]);
}

// ---------------- RoPE cos/sin table ----------------
__global__ __launch_bounds__(256) void ropetab_k(float2* __restrict__ tab) {
  const int i = blockIdx.x * 256 + threadIdx.x;   // 8192*32 entries
  const int f = i & 31, n = i >> 5;
  const float invf = exp2f(-(float)f * (13.287712379549449f / 32.0f)); // log2(10000)/32
  const float ang = (float)n * invf;
  tab[i] = make_float2(cosf(ang), sinf(ang));
}

// ---------------- fused RMSNorm + depthwise causal conv(K=4) + SiLU -> bf16 -------
__global__ __launch_bounds__(256) void rmsconv_k(const float* __restrict__ x,
                                                 const float* __restrict__ scale,
                                                 const float* __restrict__ w,
                                                 const float* __restrict__ cb,
                                                 unsigned short* __restrict__ xc) {
  __shared__ float xs[11][1024];   // rows row0-3 .. row0+7 normalized
  __shared__ float red[4];
  const int t = threadIdx.x;
  const long row0 = (long)blockIdx.x * 8;
  const bool seqstart = ((row0 & (NSEQ - 1)) == 0);
  const float4 sc = ((const float4*)scale)[t];
  for (int i = 0; i < 11; ++i) {
    if (i < 3 && seqstart) {            // block-uniform branch
      ((float4*)xs[i])[t] = make_float4(0.f, 0.f, 0.f, 0.f);
      continue;
    }
    const long r = row0 - 3 + i;
    const float4 v = ((const float4*)(x + r * DMODEL))[t];
    float ss = v.x * v.x + v.y * v.y + v.z * v.z + v.w * v.w;
#pragma unroll
    for (int off = 32; off > 0; off >>= 1) ss += __shfl_down(ss, off);
    if ((t & 63) == 0) red[t >> 6] = ss;
    __syncthreads();
    const float tot = red[0] + red[1] + red[2] + red[3];
    const float rr = rsqrtf(tot * (1.0f / DMODEL) + 1e-6f);
    float4 o;
    o.x = fminf(fmaxf(v.x * rr * sc.x, -60000.f), 60000.f);
    o.y = fminf(fmaxf(v.y * rr * sc.y, -60000.f), 60000.f);
    o.z = fminf(fmaxf(v.z * rr * sc.z, -60000.f), 60000.f);
    o.w = fminf(fmaxf(v.w * rr * sc.w, -60000.f), 60000.f);
    ((float4*)xs[i])[t] = o;
    __syncthreads();                     // xs[i] visible + red free for next row
  }
  __syncthreads();
  const int d0 = t * 4;
  float wl[4][4];
#pragma unroll
  for (int j = 0; j < 4; ++j) {
    const float4 t4 = *(const float4*)(w + (d0 + j) * 4);
    wl[j][0] = t4.x; wl[j][1] = t4.y; wl[j][2] = t4.z; wl[j][3] = t4.w;
  }
  const float4 cb4 = ((const float4*)cb)[t];
#pragma unroll
  for (int orow = 0; orow < 8; ++orow) {
    float o[4] = {0.f, 0.f, 0.f, 0.f};
#pragma unroll
    for (int k = 0; k < 4; ++k) {
      const float4 xv = ((const float4*)xs[orow + k])[t];
      o[0] += xv.x * wl[0][k]; o[1] += xv.y * wl[1][k];
      o[2] += xv.z * wl[2][k]; o[3] += xv.w * wl[3][k];
    }
    ushort4 st;
    { const float a = o[0] + cb4.x; st.x = f2bf(a * sigm(a)); }
    { const float a = o[1] + cb4.y; st.y = f2bf(a * sigm(a)); }
    { const float a = o[2] + cb4.z; st.z = f2bf(a * sigm(a)); }
    { const float a = o[3] + cb4.w; st.w = f2bf(a * sigm(a)); }
    *(ushort4*)(xc + (row0 + orow) * DMODEL + d0) = st;
  }
}

// ---------------- GEMM: C[M][Ncols] = A[M][K] @ BT[Ncols][K]^T  (bf16, f32 acc) ---
// 2-phase double-buffered pipeline (T3-min), T2 st-swizzle, T1 banded XCD decode.
// EPI==0: fused in_proj epilogue (dt->bf16 / rope(v)->bf16 / gate->bf16).
// EPI==1: residual add -> f32 out.
template <int EPI>
__global__ __launch_bounds__(256) void gemm_bt(const unsigned short* __restrict__ A,
                                               const unsigned short* __restrict__ BT,
                                               unsigned short* dtb, unsigned short* vrotb,
                                               unsigned short* gateb,
                                               const float* __restrict__ dt_bias,
                                               const float2* __restrict__ tab,
                                               float* outp, const float* __restrict__ resid) {
  __shared__ unsigned short As[2][128 * 64];
  __shared__ unsigned short Bs[2][128 * 64];
  const int tid = threadIdx.x;
  const int l = tid & 63;
  const int w = tid >> 6;
  const int wr = w >> 1, wc = w & 1;

  // T1: XCD-chunked, 8-row bm bands, bn innermost (A-panel L2 reuse, B L3-hot)
  constexpr int NBN = (EPI == 0) ? 24 : 8;   // gridDim.x
  constexpr int XB = 32;                      // bm rows per XCD (gridDim.y/8)
  const int lin = blockIdx.y * NBN + blockIdx.x;
  const int xcd = lin & 7;
  const int g = lin >> 3;
  const int band = g / (NBN * 8);
  const int j = g - band * (NBN * 8);
  const int bmoff = j / NBN;
  const int bn = j - bmoff * NBN;
  const int bm = xcd * XB + band * 8 + bmoff;

  f32x4 acc[4][4];
#pragma unroll
  for (int m = 0; m < 4; ++m)
#pragma unroll
    for (int n = 0; n < 4; ++n) acc[m][n] = {0.f, 0.f, 0.f, 0.f};

  const int lr = l >> 3;                       // row within 8-row chunk
  const int lc = ((l & 7) ^ lr) * 8;           // T2: inverse-swizzled source col
  const unsigned short* aG[4];
  const unsigned short* bG[4];
  int chofs[4];
#pragma unroll
  for (int i = 0; i < 4; ++i) {
    const int ch = w + i * 4;
    aG[i] = A + ((long)(bm * 128 + ch * 8 + lr)) * KDIM + lc;
    bG[i] = BT + ((long)(bn * 128 + ch * 8 + lr)) * KDIM + lc;
    chofs[i] = ch * 512;
  }

  // T2 read-side swizzled column (frag row % 8 == l % 8 for both A and B)
  const int sw = (l & 7) * 8;
  const int col0 = ((l >> 4) * 8) ^ sw;
  const int col1 = (32 + (l >> 4) * 8) ^ sw;

#define STAGE(buf, k0)                              \
  {                                                 \
    _Pragma("unroll")                               \
    for (int i = 0; i < 4; ++i) {                   \
      gl_lds16(aG[i] + (k0), &As[buf][chofs[i]]);   \
      gl_lds16(bG[i] + (k0), &Bs[buf][chofs[i]]);   \
    }                                               \
  }

  auto compute = [&](int cur) {
    const unsigned short* Ab = &As[cur][0];
    const unsigned short* Bb = &Bs[cur][0];
#pragma unroll
    for (int kk = 0; kk < 2; ++kk) {
      const int ck = kk ? col1 : col0;
      bf16x8 af[4], bfr[4];
#pragma unroll
      for (int m = 0; m < 4; ++m)
        af[m] = *(const bf16x8*)&Ab[(wr * 64 + m * 16 + (l & 15)) * 64 + ck];
#pragma unroll
      for (int n = 0; n < 4; ++n)
        bfr[n] = *(const bf16x8*)&Bb[(wc * 64 + n * 16 + (l & 15)) * 64 + ck];
#pragma unroll
      for (int m = 0; m < 4; ++m)
#pragma unroll
        for (int n = 0; n < 4; ++n)
          acc[m][n] = __builtin_amdgcn_mfma_f32_16x16x32_bf16(af[m], bfr[n], acc[m][n], 0, 0, 0);
    }
  };

  STAGE(0, 0);
  __syncthreads();
  int cur = 0;
  for (int kt = 0; kt < NKT - 1; ++kt) {
    STAGE(cur ^ 1, (kt + 1) * 64);   // prefetch next K-tile (drained by next barrier)
    compute(cur);
    __syncthreads();                 // vmcnt(0)+lgkmcnt(0)+barrier
    cur ^= 1;
  }
  compute(cur);                      // last tile, no barrier needed
#undef STAGE

  const int rbase = bm * 128 + wr * 64;
  const int cbase = bn * 128 + wc * 64;
  const int lr4 = (l >> 4) * 4;
  const int lc16 = l & 15;

  if constexpr (EPI == 0) {
    const int seg = cbase >> 10;   // block-uniform: 0=dt, 1=v, 2=gate
    if (seg == 0) {
#pragma unroll
      for (int m = 0; m < 4; ++m)
#pragma unroll
        for (int n = 0; n < 4; ++n) {
          const int c = (cbase & 1023) + n * 16 + lc16;
          const float bias = dt_bias[c];
#pragma unroll
          for (int j2 = 0; j2 < 4; ++j2) {
            const int row = rbase + m * 16 + lr4 + j2;
            const float a = acc[m][n][j2] + bias;
            const float e2 = exp2f(-LOG2E * fabsf(a));
            const float sp = fmaxf(a, 0.f) + 0.69314718f * log2f(1.f + e2);
            dtb[(long)row * DMODEL + c] = f2bf(fminf(fmaxf(sp, 0.001f), 2.0f));
          }
        }
    } else if (seg == 1) {
#pragma unroll
      for (int m = 0; m < 4; ++m)
#pragma unroll
        for (int n = 0; n < 2; ++n) {
          const int dd = n * 16 + lc16;          // 0..31 within head
          const int c = (cbase & 1023) + dd;
#pragma unroll
          for (int j2 = 0; j2 < 4; ++j2) {
            const int row = rbase + m * 16 + lr4 + j2;
            const int pos = row & (NSEQ - 1);
            const float2 cs = tab[pos * 32 + dd];
            const float v1 = acc[m][n][j2], v2 = acc[m][n + 2][j2];
            vrotb[(long)row * DMODEL + c]      = f2bf(v1 * cs.x - v2 * cs.y);
            vrotb[(long)row * DMODEL + c + 32] = f2bf(v1 * cs.y + v2 * cs.x);
          }
        }
    } else {
#pragma unroll
      for (int m = 0; m < 4; ++m)
#pragma unroll
        for (int n = 0; n < 4; ++n) {
          const int c = (cbase & 1023) + n * 16 + lc16;
#pragma unroll
          for (int j2 = 0; j2 < 4; ++j2) {
            const int row = rbase + m * 16 + lr4 + j2;
            gateb[(long)row * DMODEL + c] = f2bf(sigm(acc[m][n][j2]));
          }
        }
    }
  } else {
#pragma unroll
    for (int m = 0; m < 4; ++m)
#pragma unroll
      for (int n = 0; n < 4; ++n) {
        const int col = cbase + n * 16 + lc16;
#pragma unroll
        for (int j2 = 0; j2 < 4; ++j2) {
          const int row = rbase + m * 16 + lr4 + j2;
          const long o = (long)row * DMODEL + col;
          outp[o] = resid[o] + acc[m][n][j2];
        }
      }
  }
}

// ---------------- scan pass 1 (single pass, stabilizer lm=0) ----------------
__global__ __launch_bounds__(256) void scan1_k(const unsigned short* __restrict__ dt,
                                               const unsigned short* __restrict__ vrotb,
                                               float* __restrict__ Llast,
                                               float* __restrict__ bout) {
  const int idx = blockIdx.x * 256 + threadIdx.x;   // B*NCHK*D = 131072
  const int d = idx & 1023;
  const int ch = (idx >> 10) & 31;
  const int b = idx >> 15;
  const long base = ((long)b * NSEQ + ch * CHUNKC) * DMODEL + d;
  float run = 0.f, s = 0.f, L = 0.f;
#pragma unroll 4
  for (int c = 0; c < CHUNKC; ++c) {
    const float dtv = bf2f(dt[base + (long)c * DMODEL]);
    const float vv = bf2f(vrotb[base + (long)c * DMODEL]) * dtv;
    run -= dtv;
    L = fminf(fmaxf(run, -20.f), 0.f);
    s += exp2f(-LOG2E * L) * vv;
  }
  Llast[idx] = L;
  bout[idx] = exp2f(LOG2E * L) * s;
}

// ---------------- scan pass 2: cross-chunk scan per (b,d) -> carry ----------------
__global__ __launch_bounds__(256) void scan2_k(const float* __restrict__ Llast,
                                               const float* __restrict__ bout,
                                               float* __restrict__ carry) {
  const int idx = blockIdx.x * 256 + threadIdx.x;   // B*D = 4096
  const int d = idx & 1023;
  const int b = idx >> 10;
  const long base = (long)b * (NCHK * DMODEL) + d;
  float cd[NCHK];
  float run = 0.f, stab = -1e30f;
#pragma unroll
  for (int ch = 0; ch < NCHK; ++ch) {
    run += Llast[base + ch * DMODEL];
    cd[ch] = fminf(fmaxf(run, -80.f), 0.f);
    stab = fmaxf(stab, cd[ch]);
  }
  float acc = 0.f;
#pragma unroll
  for (int ch = 0; ch < NCHK; ++ch) {
    const float ncd = fminf(fmaxf(cd[ch] - stab, -20.f), 0.f);
    carry[base + ch * DMODEL] = acc * exp2f(LOG2E * ncd);
    acc += bout[base + ch * DMODEL] * exp2f(-LOG2E * ncd);
  }
}

// ------- scan pass 3: final = exp(L)*(cumsum(exp(-L)*v*dt) + carry), bf16 IN PLACE over vrot
__global__ __launch_bounds__(256) void scan3_k(const unsigned short* __restrict__ dt,
                                               unsigned short* vrotb,   // read v / write final
                                               const float* __restrict__ carry) {
  const int idx = blockIdx.x * 256 + threadIdx.x;
  const int d = idx & 1023;
  const int ch = (idx >> 10) & 31;
  const int b = idx >> 15;
  const long base = ((long)b * NSEQ + ch * CHUNKC) * DMODEL + d;
  const float ce = carry[idx];
  float run = 0.f, s = 0.f;
#pragma unroll 4
  for (int c = 0; c < CHUNKC; ++c) {
    const long o = base + (long)c * DMODEL;
    const float dtv = bf2f(dt[o]);
    const float vv = bf2f(vrotb[o]) * dtv;
    run -= dtv;
    const float L = fminf(fmaxf(run, -20.f), 0.f);
    s += exp2f(-LOG2E * L) * vv;
    vrotb[o] = f2bf(exp2f(LOG2E * L) * (s + ce));
  }
}

// ---------------- head mix (16x16) * gate -> A2 bf16 ----------------
__global__ __launch_bounds__(256) void headmix_k(const unsigned short* __restrict__ fin,
                                                 const unsigned short* __restrict__ gateb,
                                                 const float* __restrict__ hm,
                                                 unsigned short* __restrict__ A2) {
  __shared__ float mixs[256];
  const int t = threadIdx.x;
  mixs[t] = hm[t];
  __syncthreads();
  const long row = (long)blockIdx.x * 4 + (t >> 6);
  const int dd = t & 63;
  const unsigned short* f = fin + row * DMODEL + dd;
  float fv[16];
#pragma unroll
  for (int h = 0; h < 16; ++h) fv[h] = bf2f(f[h * 64]);
#pragma unroll
  for (int m = 0; m < 16; ++m) {
    float o = 0.f;
#pragma unroll
    for (int h = 0; h < 16; ++h) o += fv[h] * mixs[h * 16 + m];
    const long c = row * DMODEL + m * 64 + dd;
    A2[c] = f2bf(o * bf2f(gateb[c]));
  }
}

extern "C" void kernel_launch(void* const* d_in, const int* in_sizes, int n_in,
                              void* d_out, int out_size, void* d_ws, size_t ws_size,
                              hipStream_t stream) {
  const float* x        = (const float*)d_in[0];
  const float* nscale   = (const float*)d_in[1];
  const float* conv_w   = (const float*)d_in[2];
  const float* conv_b   = (const float*)d_in[3];
  const float* in_proj  = (const float*)d_in[4];
  const float* dt_bias  = (const float*)d_in[5];
  const float* head_mix = (const float*)d_in[6];
  const float* out_proj = (const float*)d_in[7];
  float* out = (float*)d_out;

  char* p = (char*)d_ws;
  unsigned short* W1T = (unsigned short*)p; p += (size_t)3072 * 1024 * 2;
  unsigned short* W2T = (unsigned short*)p; p += (size_t)1024 * 1024 * 2;
  float2* tab  = (float2*)p; p += (size_t)NSEQ * 32 * sizeof(float2);
  float* Llast = (float*)p;  p += (size_t)131072 * 4;
  float* bout  = (float*)p;  p += (size_t)131072 * 4;
  float* carry = (float*)p;  p += (size_t)131072 * 4;
  unsigned short* dtb   = (unsigned short*)p; p += (size_t)TOK * DMODEL * 2;
  unsigned short* xc    = (unsigned short*)p; p += (size_t)TOK * DMODEL * 2; // reused: A2
  unsigned short* vrotb = (unsigned short*)p; p += (size_t)TOK * DMODEL * 2; // reused: final
  unsigned short* gateb = (unsigned short*)p; p += (size_t)TOK * DMODEL * 2;

  transpose_bf16_k<<<dim3(96, 32), dim3(32, 8), 0, stream>>>(in_proj, W1T, 1024, 3072);
  transpose_bf16_k<<<dim3(32, 32), dim3(32, 8), 0, stream>>>(out_proj, W2T, 1024, 1024);
  ropetab_k<<<1024, 256, 0, stream>>>(tab);
  rmsconv_k<<<TOK / 8, 256, 0, stream>>>(x, nscale, conv_w, conv_b, xc);

  gemm_bt<0><<<dim3(24, 256), 256, 0, stream>>>(xc, W1T, dtb, vrotb, gateb,
                                                dt_bias, tab, nullptr, nullptr);
  scan1_k<<<512, 256, 0, stream>>>(dtb, vrotb, Llast, bout);
  scan2_k<<<16, 256, 0, stream>>>(Llast, bout, carry);
  scan3_k<<<512, 256, 0, stream>>>(dtb, vrotb, carry);
  headmix_k<<<TOK / 4, 256, 0, stream>>>(vrotb, gateb, head_mix, xc /* A2 */);
  gemm_bt<1><<<dim3(8, 256), 256, 0, stream>>>(xc, W2T, nullptr, nullptr, nullptr,
                                               nullptr, nullptr, out, x);
}